// Round 14
// baseline (804.271 us; speedup 1.0000x reference)
//
#include <hip/hip_runtime.h>
#include <hip/hip_bf16.h>
#include <hip/hip_cooperative_groups.h>

namespace cg = cooperative_groups;

#define DIN 128
#define PAD 32
#define CHUNK 4096
#define LCOL 4096

typedef __attribute__((ext_vector_type(8))) short short8;
typedef __attribute__((ext_vector_type(4))) float f32x4;
typedef __attribute__((ext_vector_type(4))) unsigned short ushort4v;
typedef __attribute__((ext_vector_type(8))) unsigned short ushort8v;

__device__ __forceinline__ unsigned short f2bf(float f) {
    unsigned int u = __float_as_uint(f);
    u += 0x7FFFu + ((u >> 16) & 1u);   // RNE
    return (unsigned short)(u >> 16);
}
__device__ __forceinline__ float bflo(unsigned int v) { return __uint_as_float(v << 16); }
__device__ __forceinline__ float bfhi(unsigned int v) { return __uint_as_float(v & 0xFFFF0000u); }

__device__ __forceinline__ void pack_w_body(const float* __restrict__ Wl,
                                            const float* __restrict__ Wr,
                                            unsigned short* __restrict__ Wp, int NT, int idx) {
    if (idx >= NT * 8 * 64) return;
    int l = idx & 63;
    int ts = idx >> 6;
    int ks = ts & 7;
    int nt = ts >> 3;
    int row = nt * 16 + (l & 15);
    int k = ks * 32 + ((l >> 4) << 3);
    const float* s = (k < 128) ? (Wl + (size_t)row * 128 + k)
                               : (Wr + (size_t)row * 128 + (k - 128));
    float4 v0 = *reinterpret_cast<const float4*>(s);
    float4 v1 = *reinterpret_cast<const float4*>(s + 4);
    unsigned short* d = Wp + (size_t)idx * 8;
    ushort4v o0 = {f2bf(v0.x), f2bf(v0.y), f2bf(v0.z), f2bf(v0.w)};
    ushort4v o1 = {f2bf(v1.x), f2bf(v1.y), f2bf(v1.z), f2bf(v1.w)};
    *reinterpret_cast<ushort4v*>(d) = o0;
    *reinterpret_cast<ushort4v*>(d + 4) = o1;
}

// gather-mean of one 64B chunk-row per edge for 16 nodes; col slice staged in LDS
__device__ __forceinline__ void agg_body(const unsigned short* __restrict__ fc,
                                         const int* __restrict__ row_ptr,
                                         const unsigned short* __restrict__ col,
                                         unsigned short* __restrict__ aggc,
                                         unsigned short* lcol, int node0, int n) {
    int t = threadIdx.x;
    int nend = min(node0 + 16, n);
    int e0 = row_ptr[node0];
    int ecnt = row_ptr[nend] - e0;
    bool inlds = (ecnt <= LCOL);
    if (inlds) {
        for (int i = t; i < ecnt; i += 256) lcol[i] = col[e0 + i];
    }
    __syncthreads();
    int lane = t & 63;
    int wave = t >> 6;
    int q = lane >> 4;
    int node = node0 + wave * 4 + q;
    int slot = (lane >> 2) & 3;
    int fb = (lane & 3) << 3;
    int beg = 0, end = 0;
    if (node < n) { beg = row_ptr[node]; end = row_ptr[node + 1]; }
    float a0 = 0.f, a1 = 0.f, a2 = 0.f, a3 = 0.f, a4 = 0.f, a5 = 0.f, a6 = 0.f, a7 = 0.f;
    int e = beg + slot;
    if (inlds) {
        for (; e + 12 < end; e += 16) {
            int c0 = lcol[e - e0];
            int c1 = lcol[e + 4 - e0];
            int c2 = lcol[e + 8 - e0];
            int c3 = lcol[e + 12 - e0];
            uint4 v0 = *reinterpret_cast<const uint4*>(fc + (size_t)c0 * 32 + fb);
            uint4 v1 = *reinterpret_cast<const uint4*>(fc + (size_t)c1 * 32 + fb);
            uint4 v2 = *reinterpret_cast<const uint4*>(fc + (size_t)c2 * 32 + fb);
            uint4 v3 = *reinterpret_cast<const uint4*>(fc + (size_t)c3 * 32 + fb);
            a0 += bflo(v0.x); a1 += bfhi(v0.x); a2 += bflo(v0.y); a3 += bfhi(v0.y);
            a4 += bflo(v0.z); a5 += bfhi(v0.z); a6 += bflo(v0.w); a7 += bfhi(v0.w);
            a0 += bflo(v1.x); a1 += bfhi(v1.x); a2 += bflo(v1.y); a3 += bfhi(v1.y);
            a4 += bflo(v1.z); a5 += bfhi(v1.z); a6 += bflo(v1.w); a7 += bfhi(v1.w);
            a0 += bflo(v2.x); a1 += bfhi(v2.x); a2 += bflo(v2.y); a3 += bfhi(v2.y);
            a4 += bflo(v2.z); a5 += bfhi(v2.z); a6 += bflo(v2.w); a7 += bfhi(v2.w);
            a0 += bflo(v3.x); a1 += bfhi(v3.x); a2 += bflo(v3.y); a3 += bfhi(v3.y);
            a4 += bflo(v3.z); a5 += bfhi(v3.z); a6 += bflo(v3.w); a7 += bfhi(v3.w);
        }
        for (; e < end; e += 4) {
            int c0 = lcol[e - e0];
            uint4 v0 = *reinterpret_cast<const uint4*>(fc + (size_t)c0 * 32 + fb);
            a0 += bflo(v0.x); a1 += bfhi(v0.x); a2 += bflo(v0.y); a3 += bfhi(v0.y);
            a4 += bflo(v0.z); a5 += bfhi(v0.z); a6 += bflo(v0.w); a7 += bfhi(v0.w);
        }
    } else {
        for (; e < end; e += 4) {
            int c0 = col[e];
            uint4 v0 = *reinterpret_cast<const uint4*>(fc + (size_t)c0 * 32 + fb);
            a0 += bflo(v0.x); a1 += bfhi(v0.x); a2 += bflo(v0.y); a3 += bfhi(v0.y);
            a4 += bflo(v0.z); a5 += bfhi(v0.z); a6 += bflo(v0.w); a7 += bfhi(v0.w);
        }
    }
    a0 += __shfl_xor(a0, 4); a1 += __shfl_xor(a1, 4); a2 += __shfl_xor(a2, 4);
    a3 += __shfl_xor(a3, 4); a4 += __shfl_xor(a4, 4); a5 += __shfl_xor(a5, 4);
    a6 += __shfl_xor(a6, 4); a7 += __shfl_xor(a7, 4);
    a0 += __shfl_xor(a0, 8); a1 += __shfl_xor(a1, 8); a2 += __shfl_xor(a2, 8);
    a3 += __shfl_xor(a3, 8); a4 += __shfl_xor(a4, 8); a5 += __shfl_xor(a5, 8);
    a6 += __shfl_xor(a6, 8); a7 += __shfl_xor(a7, 8);
    if (slot == 0 && node < n) {
        float sc = 1.0f / fmaxf((float)(end - beg), 1.0f);
        ushort8v o = {f2bf(a0 * sc), f2bf(a1 * sc), f2bf(a2 * sc), f2bf(a3 * sc),
                      f2bf(a4 * sc), f2bf(a5 * sc), f2bf(a6 * sc), f2bf(a7 * sc)};
        *reinterpret_cast<ushort8v*>(aggc + (size_t)node * 32 + fb) = o;
    }
}

__global__ __launch_bounds__(256, 3) void mega_kernel(
    const float* __restrict__ x, const int* __restrict__ src, const int* __restrict__ dst,
    const float* __restrict__ W1l, const float* __restrict__ b1, const float* __restrict__ W1r,
    const float* __restrict__ W2l, const float* __restrict__ b2, const float* __restrict__ W2r,
    const float* __restrict__ W3l, const float* __restrict__ b3, const float* __restrict__ W3r,
    float* __restrict__ out,
    int* __restrict__ bcnt, int* __restrict__ bcur, int* __restrict__ row_ptr,
    unsigned int* __restrict__ tmp, unsigned short* __restrict__ col,
    unsigned short* __restrict__ xb, unsigned short* __restrict__ aggb,
    unsigned short* __restrict__ h1b, unsigned short* __restrict__ h2b,
    unsigned short* __restrict__ y3l, float* __restrict__ y3r,
    unsigned short* __restrict__ Wp1, unsigned short* __restrict__ Wp2,
    unsigned short* __restrict__ Wp3, int n, int E) {
    __shared__ int smem[2048];   // 8 KB, aliased per phase
    cg::grid_group grid = cg::this_grid();
    const int t = threadIdx.x;
    const int G = gridDim.x;
    const int CB = (n * 16 + 255) / 256;
    const int nbn = (n + 15) / 16;
    const int n_buckets = (n + 255) / 256;
    const int nb_gemm = (n + 63) / 64;
    const size_t cs = (size_t)n * 32;

    // ===== P0: convert_x + pack_w x3 + bucket_count (bcnt/bcur pre-zeroed by memset) =====
    {
        int* h = smem;
        const int VB = CB + 40 + 784;
        for (int vb = blockIdx.x; vb < VB; vb += G) {
            int b = vb;
            if (b < CB) {
                int i = b * 256 + t;
                if (i < n * 16) {
                    int node = i >> 4;
                    int f0 = (i & 15) << 3;
                    const float* s = x + (size_t)node * DIN + f0;
                    float4 v0 = *reinterpret_cast<const float4*>(s);
                    float4 v1 = *reinterpret_cast<const float4*>(s + 4);
                    ushort8v o = {f2bf(v0.x), f2bf(v0.y), f2bf(v0.z), f2bf(v0.w),
                                  f2bf(v1.x), f2bf(v1.y), f2bf(v1.z), f2bf(v1.w)};
                    *reinterpret_cast<ushort8v*>(xb + (size_t)(f0 >> 5) * n * 32 +
                                                 (size_t)node * 32 + (f0 & 31)) = o;
                }
            } else if (b - CB < 16) {
                pack_w_body(W1l, W1r, Wp1, 8, (b - CB) * 256 + t);
            } else if (b - CB - 16 < 16) {
                pack_w_body(W2l, W2r, Wp2, 8, (b - CB - 16) * 256 + t);
            } else if (b - CB - 32 < 8) {
                pack_w_body(W3l, W3r, Wp3, 4, (b - CB - 32) * 256 + t);
            } else {
                int cb = b - CB - 40;   // 0..783
                h[t] = 0;
                __syncthreads();
                for (int i = cb * 256 + t; i < E; i += 784 * 256)
                    atomicAdd(&h[dst[i] >> 8], 1);
                __syncthreads();
                if (h[t] > 0) atomicAdd(&bcnt[t * PAD], h[t]);
                __syncthreads();
            }
        }
    }
    grid.sync();

    // ===== P1: chunk scatter (LDS histogram -> one global claim per (chunk,bucket)) =====
    {
        int* sc = smem;
        int* base = smem + 256;
        int* hist = smem + 512;
        const int VB = (E + CHUNK - 1) / CHUNK;
        for (int vb = blockIdx.x; vb < VB; vb += G) {
            int v = (t < n_buckets) ? bcnt[t * PAD] : 0;
            sc[t] = v;
            __syncthreads();
            for (int off = 1; off < 256; off <<= 1) {
                int add = (t >= off) ? sc[t - off] : 0;
                __syncthreads();
                sc[t] += add;
                __syncthreads();
            }
            int excl = sc[t] - v;
            int e0 = vb * CHUNK;
            int e1 = min(e0 + CHUNK, E);
            hist[t] = 0;
            __syncthreads();
            for (int e = e0 + t; e < e1; e += 256) atomicAdd(&hist[dst[e] >> 8], 1);
            __syncthreads();
            int hh = hist[t];
            if (hh > 0) base[t] = excl + atomicAdd(&bcur[t * PAD], hh);
            __syncthreads();
            hist[t] = 0;
            __syncthreads();
            for (int e = e0 + t; e < e1; e += 256) {
                int d = dst[e];
                int bb = d >> 8;
                int p = base[bb] + atomicAdd(&hist[bb], 1);
                tmp[p] = (unsigned int)src[e] | ((unsigned int)(d & 255) << 16);
            }
            __syncthreads();
        }
    }
    grid.sync();

    // ===== P2: bucket fill (derive row_ptr locally; sorted u16 col) =====
    {
        int* sc = smem;
        int* cur = smem + 256;
        for (int vb = blockIdx.x; vb < n_buckets; vb += G) {
            int node0 = vb << 8;
            int nn = min(256, n - node0);
            int v = (t < n_buckets) ? bcnt[t * PAD] : 0;
            sc[t] = v;
            __syncthreads();
            for (int off = 1; off < 256; off <<= 1) {
                int add = (t >= off) ? sc[t - off] : 0;
                __syncthreads();
                sc[t] += add;
                __syncthreads();
            }
            int begB = (vb == 0) ? 0 : sc[vb - 1];
            int endB = sc[vb];
            __syncthreads();
            sc[t] = 0;
            __syncthreads();
            for (int i = begB + t; i < endB; i += 256)
                atomicAdd(&sc[(tmp[i] >> 16) & 255], 1);
            __syncthreads();
            int dv = sc[t];
            __syncthreads();
            for (int off = 1; off < 256; off <<= 1) {
                int add = (t >= off) ? sc[t - off] : 0;
                __syncthreads();
                sc[t] += add;
                __syncthreads();
            }
            int r = begB + sc[t] - dv;
            if (t < nn) row_ptr[node0 + t] = r;
            cur[t] = r;
            __syncthreads();
            for (int i = begB + t; i < endB; i += 256) {
                unsigned int e = tmp[i];
                int p = atomicAdd(&cur[(e >> 16) & 255], 1);
                col[p] = (unsigned short)(e & 0xFFFFu);
            }
            if (vb == 0 && t == 0) row_ptr[n] = E;
            __syncthreads();
        }
    }
    grid.sync();

    // XCD-pinned chunk mapping for aggregate phases
    unsigned short* lcol = (unsigned short*)smem;
    const int b8 = blockIdx.x & 7;
    const int chunk4 = b8 >> 1;                       // 4 chunks, 2 XCDs each
    const int j4 = ((blockIdx.x >> 3) << 1) | (blockIdx.x & 1);
    const int stride4 = G >> 2;
    const int chunk2 = b8 >> 2;                       // 2 chunks, 4 XCDs each
    const int j2 = ((blockIdx.x >> 3) << 2) | (blockIdx.x & 3);
    const int stride2 = G >> 1;

    // ===== P3: aggregate(x) =====
    for (int nb = j4; nb < nbn; nb += stride4) {
        agg_body(xb + (size_t)chunk4 * cs, row_ptr, col, aggb + (size_t)chunk4 * cs,
                 lcol, nb * 16, n);
        __syncthreads();
    }
    grid.sync();

    // ===== P4: gemm1 -> h1 ===== (dual GEMM over K=256, relu, bf16 chunked out)
    for (int vb = blockIdx.x; vb < nb_gemm; vb += G) {
        const int lane = t & 63;
        const int wave = t >> 6;
        const int row0 = vb * 64 + wave * 16;
        const int ar = row0 + (lane & 15);
        const int kg = (lane >> 4) << 3;
        const bool ok = ar < n;
        const short8 z = {0, 0, 0, 0, 0, 0, 0, 0};
        short8 a[8];
        const unsigned short* arow = aggb + (size_t)ar * 32 + kg;
        const unsigned short* xrow = xb + (size_t)ar * 32 + kg;
#pragma unroll
        for (int ks = 0; ks < 4; ks++)
            a[ks] = ok ? *reinterpret_cast<const short8*>(arow + ks * cs) : z;
#pragma unroll
        for (int ks = 0; ks < 4; ks++)
            a[4 + ks] = ok ? *reinterpret_cast<const short8*>(xrow + ks * cs) : z;
        f32x4 acc[8];
#pragma unroll
        for (int nt = 0; nt < 8; nt++) acc[nt] = {0.f, 0.f, 0.f, 0.f};
        const unsigned short* wp = Wp1 + ((size_t)lane << 3);
#pragma unroll
        for (int nt = 0; nt < 8; nt++)
#pragma unroll
            for (int ks = 0; ks < 8; ks++) {
                short8 b = *reinterpret_cast<const short8*>(wp + ((size_t)(nt * 8 + ks) << 9));
                acc[nt] = __builtin_amdgcn_mfma_f32_16x16x32_bf16(a[ks], b, acc[nt], 0, 0, 0);
            }
        const int orow0 = row0 + ((lane >> 4) << 2);
#pragma unroll
        for (int nt = 0; nt < 8; nt++) {
            int c = nt * 16 + (lane & 15);
            float bv = b1[c];
#pragma unroll
            for (int rg = 0; rg < 4; rg++) {
                int rr = orow0 + rg;
                if (rr < n) {
                    float v = fmaxf(acc[nt][rg] + bv, 0.f);
                    h1b[(size_t)(nt >> 1) * cs + (size_t)rr * 32 +
                        ((nt & 1) * 16 + (lane & 15))] = f2bf(v);
                }
            }
        }
    }
    grid.sync();

    // ===== P5: aggregate(h1) =====
    for (int nb = j4; nb < nbn; nb += stride4) {
        agg_body(h1b + (size_t)chunk4 * cs, row_ptr, col, aggb + (size_t)chunk4 * cs,
                 lcol, nb * 16, n);
        __syncthreads();
    }
    grid.sync();

    // ===== P6: gemm2 -> h2 =====
    for (int vb = blockIdx.x; vb < nb_gemm; vb += G) {
        const int lane = t & 63;
        const int wave = t >> 6;
        const int row0 = vb * 64 + wave * 16;
        const int ar = row0 + (lane & 15);
        const int kg = (lane >> 4) << 3;
        const bool ok = ar < n;
        const short8 z = {0, 0, 0, 0, 0, 0, 0, 0};
        short8 a[8];
        const unsigned short* arow = aggb + (size_t)ar * 32 + kg;
        const unsigned short* xrow = h1b + (size_t)ar * 32 + kg;
#pragma unroll
        for (int ks = 0; ks < 4; ks++)
            a[ks] = ok ? *reinterpret_cast<const short8*>(arow + ks * cs) : z;
#pragma unroll
        for (int ks = 0; ks < 4; ks++)
            a[4 + ks] = ok ? *reinterpret_cast<const short8*>(xrow + ks * cs) : z;
        f32x4 acc[8];
#pragma unroll
        for (int nt = 0; nt < 8; nt++) acc[nt] = {0.f, 0.f, 0.f, 0.f};
        const unsigned short* wp = Wp2 + ((size_t)lane << 3);
#pragma unroll
        for (int nt = 0; nt < 8; nt++)
#pragma unroll
            for (int ks = 0; ks < 8; ks++) {
                short8 b = *reinterpret_cast<const short8*>(wp + ((size_t)(nt * 8 + ks) << 9));
                acc[nt] = __builtin_amdgcn_mfma_f32_16x16x32_bf16(a[ks], b, acc[nt], 0, 0, 0);
            }
        const int orow0 = row0 + ((lane >> 4) << 2);
#pragma unroll
        for (int nt = 0; nt < 8; nt++) {
            int c = nt * 16 + (lane & 15);
            float bv = b2[c];
#pragma unroll
            for (int rg = 0; rg < 4; rg++) {
                int rr = orow0 + rg;
                if (rr < n) {
                    float v = fmaxf(acc[nt][rg] + bv, 0.f);
                    h2b[(size_t)(nt >> 1) * cs + (size_t)rr * 32 +
                        ((nt & 1) * 16 + (lane & 15))] = f2bf(v);
                }
            }
        }
    }
    grid.sync();

    // ===== P7: gemm3 -> y3l (bf16 chunked), y3r (fp32 + bias) =====
    for (int vb = blockIdx.x; vb < nb_gemm; vb += G) {
        const int lane = t & 63;
        const int wave = t >> 6;
        const int row0 = vb * 64 + wave * 16;
        const int ar = row0 + (lane & 15);
        const int kg = (lane >> 4) << 3;
        const bool ok = ar < n;
        const short8 z = {0, 0, 0, 0, 0, 0, 0, 0};
        short8 a[4];
        const unsigned short* xrow = h2b + (size_t)ar * 32 + kg;
#pragma unroll
        for (int ks = 0; ks < 4; ks++)
            a[ks] = ok ? *reinterpret_cast<const short8*>(xrow + ks * cs) : z;
        f32x4 accL[4], accR[4];
#pragma unroll
        for (int nt = 0; nt < 4; nt++) {
            accL[nt] = {0.f, 0.f, 0.f, 0.f};
            accR[nt] = {0.f, 0.f, 0.f, 0.f};
        }
        const unsigned short* wp = Wp3 + ((size_t)lane << 3);
#pragma unroll
        for (int nt = 0; nt < 4; nt++)
#pragma unroll
            for (int ks = 0; ks < 4; ks++) {
                short8 bl = *reinterpret_cast<const short8*>(wp + ((size_t)(nt * 8 + ks) << 9));
                accL[nt] = __builtin_amdgcn_mfma_f32_16x16x32_bf16(a[ks], bl, accL[nt], 0, 0, 0);
                short8 br = *reinterpret_cast<const short8*>(wp + ((size_t)(nt * 8 + 4 + ks) << 9));
                accR[nt] = __builtin_amdgcn_mfma_f32_16x16x32_bf16(a[ks], br, accR[nt], 0, 0, 0);
            }
        const int orow0 = row0 + ((lane >> 4) << 2);
#pragma unroll
        for (int nt = 0; nt < 4; nt++) {
            int c = nt * 16 + (lane & 15);
            float bv = b3[c];
#pragma unroll
            for (int rg = 0; rg < 4; rg++) {
                int rr = orow0 + rg;
                if (rr < n) {
                    y3l[(size_t)(nt >> 1) * cs + (size_t)rr * 32 +
                        ((nt & 1) * 16 + (lane & 15))] = f2bf(accL[nt][rg]);
                    y3r[(size_t)rr * 64 + c] = accR[nt][rg] + bv;
                }
            }
        }
    }
    grid.sync();

    // ===== P8: out = mean-gather(y3l) + y3r =====
    for (int nb = j2; nb < nbn; nb += stride2) {
        int node0 = nb * 16;
        int nend = min(node0 + 16, n);
        int e0 = row_ptr[node0];
        int ecnt = row_ptr[nend] - e0;
        bool inlds = (ecnt <= LCOL);
        if (inlds) {
            for (int i = t; i < ecnt; i += 256) lcol[i] = col[e0 + i];
        }
        __syncthreads();
        int lane = t & 63;
        int wave = t >> 6;
        int q = lane >> 4;
        int node = node0 + wave * 4 + q;
        int slot = (lane >> 2) & 3;
        int fb = (lane & 3) << 3;
        const unsigned short* fc = y3l + (size_t)chunk2 * cs;
        int beg = 0, end = 0;
        if (node < n) { beg = row_ptr[node]; end = row_ptr[node + 1]; }
        float a0 = 0.f, a1 = 0.f, a2 = 0.f, a3 = 0.f, a4 = 0.f, a5 = 0.f, a6 = 0.f, a7 = 0.f;
        int e = beg + slot;
        if (inlds) {
            for (; e < end; e += 4) {
                int c0 = lcol[e - e0];
                uint4 v0 = *reinterpret_cast<const uint4*>(fc + (size_t)c0 * 32 + fb);
                a0 += bflo(v0.x); a1 += bfhi(v0.x); a2 += bflo(v0.y); a3 += bfhi(v0.y);
                a4 += bflo(v0.z); a5 += bfhi(v0.z); a6 += bflo(v0.w); a7 += bfhi(v0.w);
            }
        } else {
            for (; e < end; e += 4) {
                int c0 = col[e];
                uint4 v0 = *reinterpret_cast<const uint4*>(fc + (size_t)c0 * 32 + fb);
                a0 += bflo(v0.x); a1 += bfhi(v0.x); a2 += bflo(v0.y); a3 += bfhi(v0.y);
                a4 += bflo(v0.z); a5 += bfhi(v0.z); a6 += bflo(v0.w); a7 += bfhi(v0.w);
            }
        }
        a0 += __shfl_xor(a0, 4); a1 += __shfl_xor(a1, 4); a2 += __shfl_xor(a2, 4);
        a3 += __shfl_xor(a3, 4); a4 += __shfl_xor(a4, 4); a5 += __shfl_xor(a5, 4);
        a6 += __shfl_xor(a6, 4); a7 += __shfl_xor(a7, 4);
        a0 += __shfl_xor(a0, 8); a1 += __shfl_xor(a1, 8); a2 += __shfl_xor(a2, 8);
        a3 += __shfl_xor(a3, 8); a4 += __shfl_xor(a4, 8); a5 += __shfl_xor(a5, 8);
        a6 += __shfl_xor(a6, 8); a7 += __shfl_xor(a7, 8);
        if (slot == 0 && node < n) {
            float sc = 1.0f / fmaxf((float)(end - beg), 1.0f);
            const float* yr = y3r + (size_t)node * 64 + chunk2 * 32 + fb;
            float* o = out + (size_t)node * 64 + chunk2 * 32 + fb;
            float4 r0 = make_float4(a0 * sc + yr[0], a1 * sc + yr[1],
                                    a2 * sc + yr[2], a3 * sc + yr[3]);
            float4 r1 = make_float4(a4 * sc + yr[4], a5 * sc + yr[5],
                                    a6 * sc + yr[6], a7 * sc + yr[7]);
            *reinterpret_cast<float4*>(o) = r0;
            *reinterpret_cast<float4*>(o + 4) = r1;
        }
        __syncthreads();
    }
}

extern "C" void kernel_launch(void* const* d_in, const int* in_sizes, int n_in,
                              void* d_out, int out_size, void* d_ws, size_t ws_size,
                              hipStream_t stream) {
    const float* x = (const float*)d_in[0];
    const int* ei = (const int*)d_in[1];
    const float* W1l = (const float*)d_in[2];
    const float* b1 = (const float*)d_in[3];
    const float* W1r = (const float*)d_in[4];
    const float* W2l = (const float*)d_in[5];
    const float* b2 = (const float*)d_in[6];
    const float* W2r = (const float*)d_in[7];
    const float* W3l = (const float*)d_in[8];
    const float* b3 = (const float*)d_in[9];
    const float* W3r = (const float*)d_in[10];
    float* out = (float*)d_out;

    int n = in_sizes[0] / DIN;   // 50000
    int E = in_sizes[1] / 2;     // 800000
    const int* src = ei;
    const int* dst = ei + E;

    // ---- workspace layout (256B-aligned sections) ----
    char* p = (char*)d_ws;
    auto take = [&](size_t bytes) {
        char* r = p;
        p += (bytes + 255) & ~(size_t)255;
        return r;
    };
    int* bcnt = (int*)take(256 * PAD * 4);
    int* bcur = (int*)take(256 * PAD * 4);   // contiguous with bcnt (one memset)
    int* row_ptr = (int*)take(((size_t)n + 1) * 4);
    unsigned int* tmp = (unsigned int*)take((size_t)E * 4);
    unsigned short* col = (unsigned short*)take((size_t)E * 2 + 512);
    unsigned short* xb = (unsigned short*)take((size_t)n * DIN * 2);
    unsigned short* aggb = (unsigned short*)take((size_t)n * DIN * 2);
    unsigned short* h1b = (unsigned short*)take((size_t)n * DIN * 2);
    unsigned short* h2b = (unsigned short*)take((size_t)n * DIN * 2);
    unsigned short* y3l = (unsigned short*)take((size_t)n * 64 * 2);
    float* y3r = (float*)take((size_t)n * 64 * 4);
    unsigned short* Wp1 = (unsigned short*)take(128 * 256 * 2);
    unsigned short* Wp2 = (unsigned short*)take(128 * 256 * 2);
    unsigned short* Wp3 = (unsigned short*)take(64 * 256 * 2);

    hipMemsetAsync(bcnt, 0, 2 * 256 * PAD * 4, stream);

    int occ = 0;
    hipOccupancyMaxActiveBlocksPerMultiprocessor(&occ, mega_kernel, 256, 0);
    if (occ < 1) occ = 1;
    int grid = occ * 256;          // 256 CUs on MI355X
    if (grid > 768) grid = 768;
    grid &= ~7;                    // multiple of 8 for XCD-chunk mapping
    if (grid < 8) grid = 8;

    void* args[] = {&x, &src, &dst, &W1l, &b1, &W1r, &W2l, &b2, &W2r,
                    &W3l, &b3, &W3r, &out, &bcnt, &bcur, &row_ptr, &tmp, &col,
                    &xb, &aggb, &h1b, &h2b, &y3l, &y3r, &Wp1, &Wp2, &Wp3, &n, &E};
    hipLaunchCooperativeKernel((void*)mega_kernel, dim3(grid), dim3(256), args, 0, stream);
}

// Round 15
// 167.600 us; speedup vs baseline: 4.7988x; 4.7988x over previous
//
#include <hip/hip_runtime.h>
#include <hip/hip_bf16.h>

#define DIN 128

typedef __attribute__((ext_vector_type(8))) short short8;
typedef __attribute__((ext_vector_type(4))) float f32x4;
typedef __attribute__((ext_vector_type(4))) unsigned short ushort4v;
typedef __attribute__((ext_vector_type(8))) unsigned short ushort8v;

__device__ __forceinline__ unsigned short f2bf(float f) {
    unsigned int u = __float_as_uint(f);
    u += 0x7FFFu + ((u >> 16) & 1u);   // RNE
    return (unsigned short)(u >> 16);
}
__device__ __forceinline__ float bflo(unsigned int v) { return __uint_as_float(v << 16); }
__device__ __forceinline__ float bfhi(unsigned int v) { return __uint_as_float(v & 0xFFFF0000u); }

#define PAD 32
#define CHUNK 4096
#define LCOL 4096
#define BCAP 8192   // per-bucket tmp region capacity (mean fill 4096, sigma 64)

// ================= prep kernel: convert_x (chunked) + pack_w x3 =================
__device__ __forceinline__ void pack_w_body(const float* __restrict__ Wl,
                                            const float* __restrict__ Wr,
                                            unsigned short* __restrict__ Wp, int NT, int idx) {
    if (idx >= NT * 8 * 64) return;
    int l = idx & 63;
    int ts = idx >> 6;
    int ks = ts & 7;
    int nt = ts >> 3;
    int row = nt * 16 + (l & 15);
    int k = ks * 32 + ((l >> 4) << 3);
    const float* s = (k < 128) ? (Wl + (size_t)row * 128 + k)
                               : (Wr + (size_t)row * 128 + (k - 128));
    float4 v0 = *reinterpret_cast<const float4*>(s);
    float4 v1 = *reinterpret_cast<const float4*>(s + 4);
    unsigned short* d = Wp + (size_t)idx * 8;
    ushort4v o0 = {f2bf(v0.x), f2bf(v0.y), f2bf(v0.z), f2bf(v0.w)};
    ushort4v o1 = {f2bf(v1.x), f2bf(v1.y), f2bf(v1.z), f2bf(v1.w)};
    *reinterpret_cast<ushort4v*>(d) = o0;
    *reinterpret_cast<ushort4v*>(d + 4) = o1;
}

__global__ __launch_bounds__(256) void prep_kernel(
    const float* __restrict__ x, unsigned short* __restrict__ xb,
    const float* __restrict__ W1l, const float* __restrict__ W1r, unsigned short* __restrict__ Wp1,
    const float* __restrict__ W2l, const float* __restrict__ W2r, unsigned short* __restrict__ Wp2,
    const float* __restrict__ W3l, const float* __restrict__ W3r, unsigned short* __restrict__ Wp3,
    int n, int CB) {
    int t = threadIdx.x;
    int b = blockIdx.x;
    if (b < CB) {
        int i = b * 256 + t;
        if (i < n * 16) {
            int node = i >> 4;
            int f0 = (i & 15) << 3;
            const float* s = x + (size_t)node * DIN + f0;
            float4 v0 = *reinterpret_cast<const float4*>(s);
            float4 v1 = *reinterpret_cast<const float4*>(s + 4);
            ushort8v o = {f2bf(v0.x), f2bf(v0.y), f2bf(v0.z), f2bf(v0.w),
                          f2bf(v1.x), f2bf(v1.y), f2bf(v1.z), f2bf(v1.w)};
            *reinterpret_cast<ushort8v*>(xb + (size_t)(f0 >> 5) * n * 32 +
                                         (size_t)node * 32 + (f0 & 31)) = o;
        }
        return;
    }
    b -= CB;
    if (b < 16) { pack_w_body(W1l, W1r, Wp1, 8, b * 256 + t); return; }
    b -= 16;
    if (b < 16) { pack_w_body(W2l, W2r, Wp2, 8, b * 256 + t); return; }
    b -= 16;
    if (b < 8) { pack_w_body(W3l, W3r, Wp3, 4, b * 256 + t); return; }
}

// ================= CSR build: direct scatter into fixed-capacity bucket regions ============
__global__ __launch_bounds__(256) void chunk_scatter_kernel(const int* __restrict__ src,
                                                            const int* __restrict__ dst,
                                                            int* __restrict__ bcur,
                                                            unsigned int* __restrict__ tmp,
                                                            int E) {
    __shared__ int base[256];
    __shared__ int hist[256];
    int t = threadIdx.x;
    int e0 = blockIdx.x * CHUNK;
    int e1 = min(e0 + CHUNK, E);
    hist[t] = 0;
    __syncthreads();
    for (int e = e0 + t; e < e1; e += 256) {
        atomicAdd(&hist[dst[e] >> 8], 1);   // LDS atomic
    }
    __syncthreads();
    int hh = hist[t];
    if (hh > 0) base[t] = atomicAdd(&bcur[t * PAD], hh);
    __syncthreads();
    hist[t] = 0;
    __syncthreads();
    for (int e = e0 + t; e < e1; e += 256) {
        int d = dst[e];
        int bb = d >> 8;
        int p = base[bb] + atomicAdd(&hist[bb], 1);
        if (p < BCAP)   // clamp (statistically unreachable; prevents corruption)
            tmp[(size_t)bb * BCAP + p] =
                (unsigned int)src[e] | ((unsigned int)(d & 255) << 16);
    }
}

// one block per bucket: scan final sizes (LDS) -> global col offsets; derive row_ptr; write col
__global__ __launch_bounds__(256) void bucket_fill_kernel(const unsigned int* __restrict__ tmp,
                                                          const int* __restrict__ bcur,
                                                          int* __restrict__ row_ptr,
                                                          unsigned short* __restrict__ col,
                                                          int n, int nb_total, int E) {
    int b = blockIdx.x;
    int node0 = b << 8;
    int nn = min(256, n - node0);
    __shared__ int sc[256];
    __shared__ int cur[256];
    int t = threadIdx.x;
    int v = (t < nb_total) ? min(bcur[t * PAD], BCAP) : 0;   // final bucket sizes
    sc[t] = v;
    __syncthreads();
    for (int off = 1; off < 256; off <<= 1) {
        int add = (t >= off) ? sc[t - off] : 0;
        __syncthreads();
        sc[t] += add;
        __syncthreads();
    }
    int begB = (b == 0) ? 0 : sc[b - 1];
    int sizeB = sc[b] - begB;
    __syncthreads();
    const unsigned int* reg = tmp + (size_t)b * BCAP;
    sc[t] = 0;
    __syncthreads();
    for (int i = t; i < sizeB; i += 256)
        atomicAdd(&sc[(reg[i] >> 16) & 255], 1);   // per-node degree histogram
    __syncthreads();
    int dv = sc[t];
    __syncthreads();
    for (int off = 1; off < 256; off <<= 1) {
        int add = (t >= off) ? sc[t - off] : 0;
        __syncthreads();
        sc[t] += add;
        __syncthreads();
    }
    int r = begB + sc[t] - dv;
    if (t < nn) row_ptr[node0 + t] = r;
    cur[t] = r;
    __syncthreads();
    for (int i = t; i < sizeB; i += 256) {
        unsigned int e = reg[i];
        int p = atomicAdd(&cur[(e >> 16) & 255], 1);
        col[p] = (unsigned short)(e & 0xFFFFu);
    }
    if (b == 0 && t == 0) row_ptr[n] = E;
}

// ================= gather-aggregate (mean), chunked bf16, XCD-partitioned, LDS col slice ====
__global__ __launch_bounds__(256) void aggregate_kernel(const unsigned short* __restrict__ feat,
                                                        const int* __restrict__ row_ptr,
                                                        const unsigned short* __restrict__ col,
                                                        unsigned short* __restrict__ agg,
                                                        int n) {
    __shared__ unsigned short lcol[LCOL];
    int b = blockIdx.x;
    int chunk = (b >> 1) & 3;
    int nb = (b >> 3) * 2 + (b & 1);
    int node0 = nb * 16;
    if (node0 >= n) return;
    int nend = min(node0 + 16, n);
    int t = threadIdx.x;
    int e0 = row_ptr[node0];
    int ecnt = row_ptr[nend] - e0;
    bool inlds = (ecnt <= LCOL);
    if (inlds) {
        for (int i = t; i < ecnt; i += 256) lcol[i] = col[e0 + i];
    }
    __syncthreads();

    int lane = t & 63;
    int wave = t >> 6;
    int q = lane >> 4;
    int node = node0 + wave * 4 + q;
    int slot = (lane >> 2) & 3;
    int fb = (lane & 3) << 3;   // 8 shorts = 16B
    size_t cs = (size_t)n * 32;
    const unsigned short* fc = feat + (size_t)chunk * cs;

    int beg = 0, end = 0;
    if (node < n) { beg = row_ptr[node]; end = row_ptr[node + 1]; }
    float a0 = 0.f, a1 = 0.f, a2 = 0.f, a3 = 0.f, a4 = 0.f, a5 = 0.f, a6 = 0.f, a7 = 0.f;
    int e = beg + slot;
    if (inlds) {
        for (; e + 12 < end; e += 16) {
            int c0 = lcol[e - e0];
            int c1 = lcol[e + 4 - e0];
            int c2 = lcol[e + 8 - e0];
            int c3 = lcol[e + 12 - e0];
            uint4 v0 = *reinterpret_cast<const uint4*>(fc + (size_t)c0 * 32 + fb);
            uint4 v1 = *reinterpret_cast<const uint4*>(fc + (size_t)c1 * 32 + fb);
            uint4 v2 = *reinterpret_cast<const uint4*>(fc + (size_t)c2 * 32 + fb);
            uint4 v3 = *reinterpret_cast<const uint4*>(fc + (size_t)c3 * 32 + fb);
            a0 += bflo(v0.x); a1 += bfhi(v0.x); a2 += bflo(v0.y); a3 += bfhi(v0.y);
            a4 += bflo(v0.z); a5 += bfhi(v0.z); a6 += bflo(v0.w); a7 += bfhi(v0.w);
            a0 += bflo(v1.x); a1 += bfhi(v1.x); a2 += bflo(v1.y); a3 += bfhi(v1.y);
            a4 += bflo(v1.z); a5 += bfhi(v1.z); a6 += bflo(v1.w); a7 += bfhi(v1.w);
            a0 += bflo(v2.x); a1 += bfhi(v2.x); a2 += bflo(v2.y); a3 += bfhi(v2.y);
            a4 += bflo(v2.z); a5 += bfhi(v2.z); a6 += bflo(v2.w); a7 += bfhi(v2.w);
            a0 += bflo(v3.x); a1 += bfhi(v3.x); a2 += bflo(v3.y); a3 += bfhi(v3.y);
            a4 += bflo(v3.z); a5 += bfhi(v3.z); a6 += bflo(v3.w); a7 += bfhi(v3.w);
        }
        for (; e < end; e += 4) {
            int c0 = lcol[e - e0];
            uint4 v0 = *reinterpret_cast<const uint4*>(fc + (size_t)c0 * 32 + fb);
            a0 += bflo(v0.x); a1 += bfhi(v0.x); a2 += bflo(v0.y); a3 += bfhi(v0.y);
            a4 += bflo(v0.z); a5 += bfhi(v0.z); a6 += bflo(v0.w); a7 += bfhi(v0.w);
        }
    } else {
        for (; e < end; e += 4) {
            int c0 = col[e];
            uint4 v0 = *reinterpret_cast<const uint4*>(fc + (size_t)c0 * 32 + fb);
            a0 += bflo(v0.x); a1 += bfhi(v0.x); a2 += bflo(v0.y); a3 += bfhi(v0.y);
            a4 += bflo(v0.z); a5 += bfhi(v0.z); a6 += bflo(v0.w); a7 += bfhi(v0.w);
        }
    }
    a0 += __shfl_xor(a0, 4); a1 += __shfl_xor(a1, 4); a2 += __shfl_xor(a2, 4);
    a3 += __shfl_xor(a3, 4); a4 += __shfl_xor(a4, 4); a5 += __shfl_xor(a5, 4);
    a6 += __shfl_xor(a6, 4); a7 += __shfl_xor(a7, 4);
    a0 += __shfl_xor(a0, 8); a1 += __shfl_xor(a1, 8); a2 += __shfl_xor(a2, 8);
    a3 += __shfl_xor(a3, 8); a4 += __shfl_xor(a4, 8); a5 += __shfl_xor(a5, 8);
    a6 += __shfl_xor(a6, 8); a7 += __shfl_xor(a7, 8);
    if (slot == 0 && node < n) {
        float sc = 1.0f / fmaxf((float)(end - beg), 1.0f);
        ushort8v o = {f2bf(a0 * sc), f2bf(a1 * sc), f2bf(a2 * sc), f2bf(a3 * sc),
                      f2bf(a4 * sc), f2bf(a5 * sc), f2bf(a6 * sc), f2bf(a7 * sc)};
        *reinterpret_cast<ushort8v*>(agg + (size_t)chunk * cs + (size_t)node * 32 + fb) = o;
    }
}

// ================= MFMA dual GEMM (chunked A): h = relu([agg|x] @ Wp^T + b), bf16 chunked out
__global__ __launch_bounds__(256, 4) void mfma_gemm_kernel(
    const unsigned short* __restrict__ aggb, const unsigned short* __restrict__ xb,
    const unsigned short* __restrict__ Wp, const float* __restrict__ bias,
    unsigned short* __restrict__ outv, int n) {
    constexpr int NT = 8;
    const int lane = threadIdx.x & 63;
    const int wave = threadIdx.x >> 6;
    const int row0 = blockIdx.x * 64 + wave * 16;
    const int ar = row0 + (lane & 15);
    const int kg = (lane >> 4) << 3;
    const bool ok = ar < n;
    const size_t cs = (size_t)n * 32;

    const short8 z = {0, 0, 0, 0, 0, 0, 0, 0};
    short8 a[8];
    const unsigned short* arow = aggb + (size_t)ar * 32 + kg;
    const unsigned short* xrow = xb + (size_t)ar * 32 + kg;
#pragma unroll
    for (int ks = 0; ks < 4; ks++)
        a[ks] = ok ? *reinterpret_cast<const short8*>(arow + ks * cs) : z;
#pragma unroll
    for (int ks = 0; ks < 4; ks++)
        a[4 + ks] = ok ? *reinterpret_cast<const short8*>(xrow + ks * cs) : z;

    f32x4 acc[NT];
#pragma unroll
    for (int nt = 0; nt < NT; nt++) acc[nt] = {0.f, 0.f, 0.f, 0.f};

    const unsigned short* wp = Wp + ((size_t)lane << 3);
#pragma unroll
    for (int nt = 0; nt < NT; nt++) {
#pragma unroll
        for (int ks = 0; ks < 8; ks++) {
            short8 b = *reinterpret_cast<const short8*>(wp + ((size_t)(nt * 8 + ks) << 9));
            acc[nt] = __builtin_amdgcn_mfma_f32_16x16x32_bf16(a[ks], b, acc[nt], 0, 0, 0);
        }
    }

    const int orow0 = row0 + ((lane >> 4) << 2);
#pragma unroll
    for (int nt = 0; nt < NT; nt++) {
        int c = nt * 16 + (lane & 15);
        float bv = bias[c];
#pragma unroll
        for (int rg = 0; rg < 4; rg++) {
            int rr = orow0 + rg;
            if (rr < n) {
                float v = fmaxf(acc[nt][rg] + bv, 0.f);
                outv[(size_t)(nt >> 1) * cs + (size_t)rr * 32 + ((nt & 1) * 16 + (lane & 15))] =
                    f2bf(v);
            }
        }
    }
}

// ================= layer-3 dual-output GEMM: y3l = h2@W3l^T (bf16 chunked), y3r = h2@W3r^T + b3
__global__ __launch_bounds__(256, 4) void gemm3_kernel(
    const unsigned short* __restrict__ h2, const unsigned short* __restrict__ Wp3,
    const float* __restrict__ bias, unsigned short* __restrict__ y3l,
    float* __restrict__ y3r, int n) {
    const int lane = threadIdx.x & 63;
    const int wave = threadIdx.x >> 6;
    const int row0 = blockIdx.x * 64 + wave * 16;
    const int ar = row0 + (lane & 15);
    const int kg = (lane >> 4) << 3;
    const bool ok = ar < n;
    const size_t cs = (size_t)n * 32;

    const short8 z = {0, 0, 0, 0, 0, 0, 0, 0};
    short8 a[4];
    const unsigned short* xrow = h2 + (size_t)ar * 32 + kg;
#pragma unroll
    for (int ks = 0; ks < 4; ks++)
        a[ks] = ok ? *reinterpret_cast<const short8*>(xrow + ks * cs) : z;

    f32x4 accL[4], accR[4];
#pragma unroll
    for (int nt = 0; nt < 4; nt++) { accL[nt] = {0.f, 0.f, 0.f, 0.f}; accR[nt] = {0.f, 0.f, 0.f, 0.f}; }

    const unsigned short* wp = Wp3 + ((size_t)lane << 3);
#pragma unroll
    for (int nt = 0; nt < 4; nt++) {
#pragma unroll
        for (int ks = 0; ks < 4; ks++) {
            short8 bl = *reinterpret_cast<const short8*>(wp + ((size_t)(nt * 8 + ks) << 9));
            accL[nt] = __builtin_amdgcn_mfma_f32_16x16x32_bf16(a[ks], bl, accL[nt], 0, 0, 0);
            short8 br = *reinterpret_cast<const short8*>(wp + ((size_t)(nt * 8 + 4 + ks) << 9));
            accR[nt] = __builtin_amdgcn_mfma_f32_16x16x32_bf16(a[ks], br, accR[nt], 0, 0, 0);
        }
    }

    const int orow0 = row0 + ((lane >> 4) << 2);
#pragma unroll
    for (int nt = 0; nt < 4; nt++) {
        int c = nt * 16 + (lane & 15);
        float bv = bias[c];
#pragma unroll
        for (int rg = 0; rg < 4; rg++) {
            int rr = orow0 + rg;
            if (rr < n) {
                y3l[(size_t)(nt >> 1) * cs + (size_t)rr * 32 + ((nt & 1) * 16 + (lane & 15))] =
                    f2bf(accL[nt][rg]);
                y3r[(size_t)rr * 64 + c] = accR[nt][rg] + bv;
            }
        }
    }
}

// ================= final: out = mean-gather(y3l) + y3r  (fp32 row-major [n][64]) =============
__global__ __launch_bounds__(256) void agg_add_kernel(const unsigned short* __restrict__ y3l,
                                                      const float* __restrict__ y3r,
                                                      const int* __restrict__ row_ptr,
                                                      const unsigned short* __restrict__ col,
                                                      float* __restrict__ out, int n) {
    __shared__ unsigned short lcol[LCOL];
    int b = blockIdx.x;
    int chunk = (b >> 2) & 1;
    int nb = (b >> 3) * 4 + (b & 3);
    int node0 = nb * 16;
    if (node0 >= n) return;
    int nend = min(node0 + 16, n);
    int t = threadIdx.x;
    int e0 = row_ptr[node0];
    int ecnt = row_ptr[nend] - e0;
    bool inlds = (ecnt <= LCOL);
    if (inlds) {
        for (int i = t; i < ecnt; i += 256) lcol[i] = col[e0 + i];
    }
    __syncthreads();

    int lane = t & 63;
    int wave = t >> 6;
    int q = lane >> 4;
    int node = node0 + wave * 4 + q;
    int slot = (lane >> 2) & 3;
    int fb = (lane & 3) << 3;
    size_t cs = (size_t)n * 32;
    const unsigned short* fc = y3l + (size_t)chunk * cs;

    int beg = 0, end = 0;
    if (node < n) { beg = row_ptr[node]; end = row_ptr[node + 1]; }
    float a0 = 0.f, a1 = 0.f, a2 = 0.f, a3 = 0.f, a4 = 0.f, a5 = 0.f, a6 = 0.f, a7 = 0.f;
    int e = beg + slot;
    if (inlds) {
        for (; e + 12 < end; e += 16) {
            int c0 = lcol[e - e0];
            int c1 = lcol[e + 4 - e0];
            int c2 = lcol[e + 8 - e0];
            int c3 = lcol[e + 12 - e0];
            uint4 v0 = *reinterpret_cast<const uint4*>(fc + (size_t)c0 * 32 + fb);
            uint4 v1 = *reinterpret_cast<const uint4*>(fc + (size_t)c1 * 32 + fb);
            uint4 v2 = *reinterpret_cast<const uint4*>(fc + (size_t)c2 * 32 + fb);
            uint4 v3 = *reinterpret_cast<const uint4*>(fc + (size_t)c3 * 32 + fb);
            a0 += bflo(v0.x); a1 += bfhi(v0.x); a2 += bflo(v0.y); a3 += bfhi(v0.y);
            a4 += bflo(v0.z); a5 += bfhi(v0.z); a6 += bflo(v0.w); a7 += bfhi(v0.w);
            a0 += bflo(v1.x); a1 += bfhi(v1.x); a2 += bflo(v1.y); a3 += bfhi(v1.y);
            a4 += bflo(v1.z); a5 += bfhi(v1.z); a6 += bflo(v1.w); a7 += bfhi(v1.w);
            a0 += bflo(v2.x); a1 += bfhi(v2.x); a2 += bflo(v2.y); a3 += bfhi(v2.y);
            a4 += bflo(v2.z); a5 += bfhi(v2.z); a6 += bflo(v2.w); a7 += bfhi(v2.w);
            a0 += bflo(v3.x); a1 += bfhi(v3.x); a2 += bflo(v3.y); a3 += bfhi(v3.y);
            a4 += bflo(v3.z); a5 += bfhi(v3.z); a6 += bflo(v3.w); a7 += bfhi(v3.w);
        }
        for (; e < end; e += 4) {
            int c0 = lcol[e - e0];
            uint4 v0 = *reinterpret_cast<const uint4*>(fc + (size_t)c0 * 32 + fb);
            a0 += bflo(v0.x); a1 += bfhi(v0.x); a2 += bflo(v0.y); a3 += bfhi(v0.y);
            a4 += bflo(v0.z); a5 += bfhi(v0.z); a6 += bflo(v0.w); a7 += bfhi(v0.w);
        }
    } else {
        for (; e < end; e += 4) {
            int c0 = col[e];
            uint4 v0 = *reinterpret_cast<const uint4*>(fc + (size_t)c0 * 32 + fb);
            a0 += bflo(v0.x); a1 += bfhi(v0.x); a2 += bflo(v0.y); a3 += bfhi(v0.y);
            a4 += bflo(v0.z); a5 += bfhi(v0.z); a6 += bflo(v0.w); a7 += bfhi(v0.w);
        }
    }
    a0 += __shfl_xor(a0, 4); a1 += __shfl_xor(a1, 4); a2 += __shfl_xor(a2, 4);
    a3 += __shfl_xor(a3, 4); a4 += __shfl_xor(a4, 4); a5 += __shfl_xor(a5, 4);
    a6 += __shfl_xor(a6, 4); a7 += __shfl_xor(a7, 4);
    a0 += __shfl_xor(a0, 8); a1 += __shfl_xor(a1, 8); a2 += __shfl_xor(a2, 8);
    a3 += __shfl_xor(a3, 8); a4 += __shfl_xor(a4, 8); a5 += __shfl_xor(a5, 8);
    a6 += __shfl_xor(a6, 8); a7 += __shfl_xor(a7, 8);
    if (slot == 0 && node < n) {
        float sc = 1.0f / fmaxf((float)(end - beg), 1.0f);
        const float* yr = y3r + (size_t)node * 64 + chunk * 32 + fb;
        float* o = out + (size_t)node * 64 + chunk * 32 + fb;
        float4 r0 = make_float4(a0 * sc + yr[0], a1 * sc + yr[1], a2 * sc + yr[2], a3 * sc + yr[3]);
        float4 r1 = make_float4(a4 * sc + yr[4], a5 * sc + yr[5], a6 * sc + yr[6], a7 * sc + yr[7]);
        *reinterpret_cast<float4*>(o) = r0;
        *reinterpret_cast<float4*>(o + 4) = r1;
    }
}

extern "C" void kernel_launch(void* const* d_in, const int* in_sizes, int n_in,
                              void* d_out, int out_size, void* d_ws, size_t ws_size,
                              hipStream_t stream) {
    const float* x = (const float*)d_in[0];
    const int* ei = (const int*)d_in[1];
    const float* W1l = (const float*)d_in[2];
    const float* b1 = (const float*)d_in[3];
    const float* W1r = (const float*)d_in[4];
    const float* W2l = (const float*)d_in[5];
    const float* b2 = (const float*)d_in[6];
    const float* W2r = (const float*)d_in[7];
    const float* W3l = (const float*)d_in[8];
    const float* b3 = (const float*)d_in[9];
    const float* W3r = (const float*)d_in[10];
    float* out = (float*)d_out;

    const int n = in_sizes[0] / DIN;   // 50000
    const int E = in_sizes[1] / 2;     // 800000
    const int* src = ei;
    const int* dst = ei + E;

    // ---- workspace layout (256B-aligned sections) ----
    char* p = (char*)d_ws;
    auto take = [&](size_t bytes) {
        char* r = p;
        p += (bytes + 255) & ~(size_t)255;
        return r;
    };
    int* bcur = (int*)take(256 * PAD * 4);
    int* row_ptr = (int*)take(((size_t)n + 1) * 4);
    unsigned int* tmp = (unsigned int*)take((size_t)256 * BCAP * 4);   // bucket regions
    unsigned short* col = (unsigned short*)take((size_t)E * 2 + 512);
    unsigned short* xb = (unsigned short*)take((size_t)n * DIN * 2);
    unsigned short* aggb = (unsigned short*)take((size_t)n * DIN * 2);
    unsigned short* h1b = (unsigned short*)take((size_t)n * DIN * 2);
    unsigned short* h2b = (unsigned short*)take((size_t)n * DIN * 2);
    unsigned short* y3l = (unsigned short*)take((size_t)n * 64 * 2);
    float* y3r = (float*)take((size_t)n * 64 * 4);
    unsigned short* Wp1 = (unsigned short*)take(128 * 256 * 2);
    unsigned short* Wp2 = (unsigned short*)take(128 * 256 * 2);
    unsigned short* Wp3 = (unsigned short*)take(64 * 256 * 2);

    const int n_buckets = (n + 255) / 256;        // 196
    const int nbn = (n + 15) / 16;                // 3125 node-blocks
    const int nbn2 = (nbn + 1) & ~1;              // even
    const int nb_agg = 4 * nbn2;
    const int nbn4 = (nbn + 3) & ~3;              // mult of 4
    const int nb_agg3 = 2 * nbn4;
    const int nb_gemm = (n + 63) / 64;
    const int nb_chunk = (E + CHUNK - 1) / CHUNK;
    const int CB = (n * 16 + 255) / 256;
    const int nb_prep = CB + 16 + 16 + 8;

    // ---- prep (convert + pack); cursor zero via memset ----
    hipMemsetAsync(bcur, 0, 256 * PAD * 4, stream);
    prep_kernel<<<nb_prep, 256, 0, stream>>>(x, xb, W1l, W1r, Wp1, W2l, W2r, Wp2,
                                             W3l, W3r, Wp3, n, CB);

    // ---- CSR build (direct region scatter, no counting pass) ----
    chunk_scatter_kernel<<<nb_chunk, 256, 0, stream>>>(src, dst, bcur, tmp, E);
    bucket_fill_kernel<<<n_buckets, 256, 0, stream>>>(tmp, bcur, row_ptr, col, n, n_buckets, E);

    // ---- layer 1 ----
    aggregate_kernel<<<nb_agg, 256, 0, stream>>>(xb, row_ptr, col, aggb, n);
    mfma_gemm_kernel<<<nb_gemm, 256, 0, stream>>>(aggb, xb, Wp1, b1, h1b, n);

    // ---- layer 2 ----
    aggregate_kernel<<<nb_agg, 256, 0, stream>>>(h1b, row_ptr, col, aggb, n);
    mfma_gemm_kernel<<<nb_gemm, 256, 0, stream>>>(aggb, h1b, Wp2, b2, h2b, n);

    // ---- layer 3: GEMM first (linearity), then gather-add ----
    gemm3_kernel<<<nb_gemm, 256, 0, stream>>>(h2b, Wp3, b3, y3l, y3r, n);
    agg_add_kernel<<<nb_agg3, 256, 0, stream>>>(y3l, y3r, row_ptr, col, out, n);
}